// Round 10
// baseline (206.197 us; speedup 1.0000x reference)
//
#include <hip/hip_runtime.h>

// CRF log-partition forward, MI355X. 64 blocks (1 per sequence) x 256 threads
// (4 waves, pinned 1 wave/EU). Round-10 change: QUAD-ONLY reduction.
// Round-9's chain had three serialized LDS-latency hops per step (chunk read,
// ds_swizzle xor4, result write+drain). New tile: k = tid&3 -> i-chunk
// [32k,32k+32) (8x b128), g = tid>>2 -> tag pair {2g,2g+1} held as one f2.
// The 4-way i-combine is DPP xor1+xor2 only -- the swizzle hop is gone.
// Writers k<2 store tag 2g+k (32 consecutive words per wave, conflict-free).
//
// E tile: 32 NAMED f2 registers (64 VGPRs) -- named scalars + waves_per_eu(1,1)
// keep it in arch VGPRs (round-9 lesson: default heuristic parks it in AGPRs).
// Barrier: lgkmcnt-only inline asm (cross-wave data is LDS-only) so the
// distance-4 emission prefetch stays in flight across steps.
//
// Linear-domain recurrence with exact power-of-2 renormalization:
//   q'_j = exp2(e_j*log2e) * (sum_i q_i E_ij) * 2^(-eS),  eS = exponent(q_0)
//   o    += eS   (integer, exact)
// alpha_j = ln2 * (o + log2 q_j). Final: ln2*(o + log2 sum_j q_j*exp(end_j)).

#define LOG2E 1.4426950408889634f
#define LN2   0.6931471805599453f

// LDS-only workgroup barrier: no vmcnt drain (cross-wave data is LDS only).
#define LDS_BARRIER() asm volatile("s_waitcnt lgkmcnt(0)\n\ts_barrier" ::: "memory")

typedef float f2 __attribute__((ext_vector_type(2)));

template <int CTRL>
__device__ __forceinline__ float dpp_f(float x) {
    return __int_as_float(
        __builtin_amdgcn_mov_dpp(__float_as_int(x), CTRL, 0xF, 0xF, false));
}
template <int CTRL>
__device__ __forceinline__ f2 dpp_f2(f2 x) {
    f2 r;
    r.x = dpp_f<CTRL>(x.x);
    r.y = dpp_f<CTRL>(x.y);
    return r;
}
// quad_perm codes: xor1 = 0xB1, xor2 = 0x4E

__global__ __launch_bounds__(256)
__attribute__((amdgpu_waves_per_eu(1, 1)))
void crf_forward(
    const float* __restrict__ emissions,   // [64, 512, 128]
    const float* __restrict__ transitions, // [128, 128]
    const float* __restrict__ start_t,     // [128]
    const float* __restrict__ end_t,       // [128]
    const int*   __restrict__ lengths,     // [64]
    float* __restrict__ out)               // [64]
{
    constexpr int N = 128;
    constexpr int L = 512;
    constexpr int PW = 36;   // 32 floats + 4 pad per chunk (144 B, 16B-aligned)
    const int b   = blockIdx.x;
    const int tid = threadIdx.x;
    const int g   = tid >> 2;            // tag pair {2g, 2g+1}
    const int k   = tid & 3;             // i-chunk: i in [32k, 32k+32)
    const int jw  = 2 * g + (k & 1);     // this lane's output tag (writer iff k<2)

    __shared__ alignas(16) float pbuf[2][4 * PW];
    __shared__ float wsum[2];

    // ---- one-time: 32i x 2j E tile as 32 NAMED f2 registers.
    f2 E_0,  E_1,  E_2,  E_3,  E_4,  E_5,  E_6,  E_7;
    f2 E_8,  E_9,  E_10, E_11, E_12, E_13, E_14, E_15;
    f2 E_16, E_17, E_18, E_19, E_20, E_21, E_22, E_23;
    f2 E_24, E_25, E_26, E_27, E_28, E_29, E_30, E_31;
    {
        const float* tb = transitions + (size_t)(32 * k) * N + 2 * g;
#define INIT_E(ii)                                                             \
        {                                                                      \
            f2 tv = *reinterpret_cast<const f2*>(tb + (size_t)(ii) * N);       \
            E_##ii.x = __builtin_amdgcn_exp2f(tv.x * LOG2E);                   \
            E_##ii.y = __builtin_amdgcn_exp2f(tv.y * LOG2E);                   \
        }
        INIT_E(0)  INIT_E(1)  INIT_E(2)  INIT_E(3)
        INIT_E(4)  INIT_E(5)  INIT_E(6)  INIT_E(7)
        INIT_E(8)  INIT_E(9)  INIT_E(10) INIT_E(11)
        INIT_E(12) INIT_E(13) INIT_E(14) INIT_E(15)
        INIT_E(16) INIT_E(17) INIT_E(18) INIT_E(19)
        INIT_E(20) INIT_E(21) INIT_E(22) INIT_E(23)
        INIT_E(24) INIT_E(25) INIT_E(26) INIT_E(27)
        INIT_E(28) INIT_E(29) INIT_E(30) INIT_E(31)
#undef INIT_E
    }

    const int len = lengths[b];
    const float* eb = emissions + (size_t)b * L * N;

    // ---- init: q_j = exp2((start_j + e0_j)*log2e)
    if (tid < N) {
        float q = __builtin_amdgcn_exp2f((start_t[tid] + eb[tid]) * LOG2E);
        pbuf[0][(tid >> 5) * PW + (tid & 31)] = q;
    }
    int o = 0;
    int cur = 0;
    LDS_BARRIER();

    auto clampt = [&](int tt) { return tt < len ? tt : len - 1; };
    auto ldE = [&](int tt) { return eb[(size_t)tt * N + jw]; };

    auto STEP = [&](float e_cur) {
        // normalizer source (b32 broadcast) + my 32-float chunk (8x b128;
        // quad chunk bases 0/36/72/108 words -> 16 distinct banks, no conflict)
        float p0 = pbuf[cur][0];
        const float4* pv = reinterpret_cast<const float4*>(&pbuf[cur][k * PW]);
        float4 v0 = pv[0], v1 = pv[1], v2 = pv[2], v3 = pv[3];
        float4 v4 = pv[4], v5 = pv[5], v6 = pv[6], v7 = pv[7];

        float expE = __builtin_amdgcn_exp2f(e_cur * LOG2E);
        int eS = (int)((__float_as_uint(p0) >> 23) & 0xFFu) - 127;
        o += eS;
        float scale = __uint_as_float((unsigned)(127 - eS) << 23);
        float es = expE * scale;   // off the critical tail

        // 32 pk-FMA over the 32i x 2j tile, 4 accumulator chains (depth 8)
        f2 a0 = {0.f, 0.f}, a1 = {0.f, 0.f}, a2 = {0.f, 0.f}, a3 = {0.f, 0.f};
#define ACC(vc, ii, acc)                                                       \
        {                                                                      \
            f2 pp = {vc, vc};                                                  \
            acc = __builtin_elementwise_fma(pp, E_##ii, acc);                  \
        }
        ACC(v0.x, 0,  a0) ACC(v0.y, 1,  a1) ACC(v0.z, 2,  a2) ACC(v0.w, 3,  a3)
        ACC(v1.x, 4,  a0) ACC(v1.y, 5,  a1) ACC(v1.z, 6,  a2) ACC(v1.w, 7,  a3)
        ACC(v2.x, 8,  a0) ACC(v2.y, 9,  a1) ACC(v2.z, 10, a2) ACC(v2.w, 11, a3)
        ACC(v3.x, 12, a0) ACC(v3.y, 13, a1) ACC(v3.z, 14, a2) ACC(v3.w, 15, a3)
        ACC(v4.x, 16, a0) ACC(v4.y, 17, a1) ACC(v4.z, 18, a2) ACC(v4.w, 19, a3)
        ACC(v5.x, 20, a0) ACC(v5.y, 21, a1) ACC(v5.z, 22, a2) ACC(v5.w, 23, a3)
        ACC(v6.x, 24, a0) ACC(v6.y, 25, a1) ACC(v6.z, 26, a2) ACC(v6.w, 27, a3)
        ACC(v7.x, 28, a0) ACC(v7.y, 29, a1) ACC(v7.z, 30, a2) ACC(v7.w, 31, a3)
#undef ACC
        f2 d = (a0 + a1) + (a2 + a3);

        // quad butterfly (DPP only) -> all 4 quad lanes hold full sums
        d += dpp_f2<0xB1>(d);
        d += dpp_f2<0x4E>(d);
        float dm = (k & 1) ? d.y : d.x;

        float pn = es * dm;
        cur ^= 1;
        if (k < 2) pbuf[cur][(jw >> 5) * PW + (jw & 31)] = pn;
        LDS_BARRIER();
    };

    // ---- main loop: distance-4 emission prefetch, manual 4-way unroll
    float ra = ldE(clampt(1));
    float rb = ldE(clampt(2));
    float rc = ldE(clampt(3));
    float rd = ldE(clampt(4));

    int t = 1;
    while (t < len) {
        STEP(ra); ra = ldE(clampt(t + 4)); ++t; if (t >= len) break;
        STEP(rb); rb = ldE(clampt(t + 4)); ++t; if (t >= len) break;
        STEP(rc); rc = ldE(clampt(t + 4)); ++t; if (t >= len) break;
        STEP(rd); rd = ldE(clampt(t + 4)); ++t;
    }

    // ---- finalize: out[b] = ln2 * (o + log2(sum_j q_j * exp2(end_j*log2e)))
    if (tid < N) {
        float q = pbuf[cur][(tid >> 5) * PW + (tid & 31)];
        float vend = q * __builtin_amdgcn_exp2f(end_t[tid] * LOG2E);
        #pragma unroll
        for (int m = 1; m < 64; m <<= 1) vend += __shfl_xor(vend, m);
        if ((tid & 63) == 0) wsum[tid >> 6] = vend;
    }
    LDS_BARRIER();
    if (tid == 0)
        out[b] = LN2 * ((float)o + __builtin_amdgcn_logf(wsum[0] + wsum[1]));
}

extern "C" void kernel_launch(void* const* d_in, const int* in_sizes, int n_in,
                              void* d_out, int out_size, void* d_ws, size_t ws_size,
                              hipStream_t stream) {
    const float* emissions   = (const float*)d_in[0];
    const float* transitions = (const float*)d_in[1];
    const float* start_t     = (const float*)d_in[2];
    const float* end_t       = (const float*)d_in[3];
    const int*   lengths     = (const int*)d_in[4];
    float* out = (float*)d_out;

    crf_forward<<<dim3(64), dim3(256), 0, stream>>>(
        emissions, transitions, start_t, end_t, lengths, out);
}